// Round 2
// baseline (112.047 us; speedup 1.0000x reference)
//
#include <hip/hip_runtime.h>
#include <stdint.h>

// Problem: B=32, P=16, E=50000, H=128
#define E_DIM 50000
#define EP    50048          // E padded to multiple of 64
#define HD    128
#define BD    32
#define PD    16
#define MD    512            // B*P
#define KCHUNK 768           // 24 k-steps of 32
#define NKC   66             // ceil(EP/KCHUNK); last chunk = 128 (4 steps)
#define EPSF  1e-5f

typedef short short8 __attribute__((ext_vector_type(8)));   // 8 bf16 (4 VGPRs)
typedef float f32x4  __attribute__((ext_vector_type(4)));

__device__ __forceinline__ uint16_t f2bf(float f) {
  uint32_t u = __float_as_uint(f);
  u += 0x7FFFu + ((u >> 16) & 1u);           // round-to-nearest-even
  return (uint16_t)(u >> 16);
}

// ---------------------------------------------------------------------------
// Kernel 1: emb [E][H] fp32 -> embT [H][EP] bf16 (transposed, row0 zeroed,
// e >= E_DIM zero-padded). LDS tile transpose with XOR swizzle.
// ---------------------------------------------------------------------------
__global__ __launch_bounds__(256) void k_embT(const float* __restrict__ emb,
                                              uint16_t* __restrict__ embT) {
  __shared__ __align__(16) uint16_t lds[HD * 64];   // [h][e_local], swizzled
  const int t  = threadIdx.x;
  const int e0 = blockIdx.x * 64;

#pragma unroll
  for (int pass = 0; pass < 8; ++pass) {
    const int el = pass * 8 + (t >> 5);       // 0..63
    const int h  = (t & 31) * 4;              // 0..124
    const int eg = e0 + el;
    float4 v = {0.f, 0.f, 0.f, 0.f};
    if (eg < E_DIM && eg != 0)                // padding_idx=0 -> zero row
      v = *(const float4*)(emb + (size_t)eg * HD + h);
    const uint16_t q0 = f2bf(v.x), q1 = f2bf(v.y), q2 = f2bf(v.z), q3 = f2bf(v.w);
    lds[(h + 0) * 64 + (el ^ (((h + 0) & 7) << 3))] = q0;
    lds[(h + 1) * 64 + (el ^ (((h + 1) & 7) << 3))] = q1;
    lds[(h + 2) * 64 + (el ^ (((h + 2) & 7) << 3))] = q2;
    lds[(h + 3) * 64 + (el ^ (((h + 3) & 7) << 3))] = q3;
  }
  __syncthreads();
#pragma unroll
  for (int pass = 0; pass < 8; ++pass) {
    const int hr  = pass * 16 + (t >> 4);     // 0..127
    const int el4 = (t & 15) * 4;             // 0..60
    uint2 d = *(const uint2*)(lds + hr * 64 + (el4 ^ ((hr & 7) << 3)));
    *(uint2*)(embT + (size_t)hr * EP + e0 + el4) = d;
  }
}

// ---------------------------------------------------------------------------
// Kernel 2: barrier-free partial GEMM.
// Wave tile = 16 rows x 32 cols (acc = 2 x f32x4 = 8 VGPRs). A loaded
// global->reg (8 contiguous int32 per lane), converted to bf16 {0,1} with
// 2 VALU per 2 elems. B loaded per-lane from embT (L2/L3-resident).
// No LDS, no __syncthreads in the K-loop -> deep pipelining + high occupancy.
// Grid = NKC * 32 m-blocks = 2112 blocks x 4 waves = 8448 waves.
// ---------------------------------------------------------------------------
__global__ __launch_bounds__(256, 6) void k_gemm(const int* __restrict__ inp,
                                                 const uint16_t* __restrict__ embT,
                                                 float* __restrict__ part,
                                                 float* __restrict__ cntp) {
  const int t    = threadIdx.x;
  const int lane = t & 63;
  const int w    = t >> 6;               // wave id = column group (32 cols)
  const int mb   = blockIdx.x & 31;      // 16-row block
  const int kc   = blockIdx.x >> 5;      // 768-wide k chunk
  const int e0   = kc * KCHUNK;
  const int nst  = min(24, (EP - e0) >> 5);   // 24, or 4 for the last chunk

  const int r16 = lane & 15;
  const int kg  = (lane >> 4) << 3;      // 0,8,16,24 within a 32-k step
  const int row = mb * 16 + r16;

  const int*      ap  = inp  + (size_t)row * E_DIM + e0 + kg;
  const uint16_t* bp0 = embT + (size_t)(w * 32 + r16)      * EP + e0 + kg;
  const uint16_t* bp1 = embT + (size_t)(w * 32 + 16 + r16) * EP + e0 + kg;

  f32x4 acc0 = {0.f, 0.f, 0.f, 0.f};
  f32x4 acc1 = {0.f, 0.f, 0.f, 0.f};
  uint32_t cnt32 = 0;
  int e = e0 + kg;

#pragma unroll 4
  for (int s = 0; s < nst; ++s) {
    int4 v0 = {0, 0, 0, 0}, v1 = {0, 0, 0, 0};
    if (e < E_DIM) {                       // e % 8 == 0, E_DIM % 8 == 0: all-or-none
      v0 = *(const int4*)ap;
      v1 = *(const int4*)(ap + 4);
    }
    const short8 b0 = *(const short8*)bp0;
    const short8 b1 = *(const short8*)bp1;

    const uint32_t w01 = (uint32_t)v0.x | ((uint32_t)v0.y << 16);
    const uint32_t w23 = (uint32_t)v0.z | ((uint32_t)v0.w << 16);
    const uint32_t w45 = (uint32_t)v1.x | ((uint32_t)v1.y << 16);
    const uint32_t w67 = (uint32_t)v1.z | ((uint32_t)v1.w << 16);
    if (w == 0) cnt32 += w01 + w23 + w45 + w67;   // halfword-packed counts

    union { uint32_t u[4]; short8 s8; } af;
    af.u[0] = w01 * 0x3F80u;               // {0,1} -> bf16 {0,1.0}, pairwise
    af.u[1] = w23 * 0x3F80u;
    af.u[2] = w45 * 0x3F80u;
    af.u[3] = w67 * 0x3F80u;

    acc0 = __builtin_amdgcn_mfma_f32_16x16x32_bf16(af.s8, b0, acc0, 0, 0, 0);
    acc1 = __builtin_amdgcn_mfma_f32_16x16x32_bf16(af.s8, b1, acc1, 0, 0, 0);

    ap += 32; bp0 += 32; bp1 += 32; e += 32;
  }

  // ---- epilogue: partial tile [kc][row][col] fp32 ----
  const int orow = mb * 16 + ((lane >> 4) << 2);      // C/D: row=(l>>4)*4+j
  float* pt = part + (size_t)kc * (MD * HD) + (size_t)orow * HD + w * 32 + r16;
#pragma unroll
  for (int j = 0; j < 4; ++j) {
    pt[j * HD]      = acc0[j];             // cols +0..15
    pt[j * HD + 16] = acc1[j];             // cols +16..31
  }

  // ---- per-row mask counts (one wave per block) ----
  if (w == 0) {
    int c = (int)((cnt32 & 0xFFFFu) + (cnt32 >> 16));
    c += __shfl_down(c, 32);
    c += __shfl_down(c, 16);
    if (lane < 16) cntp[kc * MD + mb * 16 + lane] = (float)c;
  }
}

// ---------------------------------------------------------------------------
// Kernel 3: reduce partials over kc -> path_emb [512][128]
// ---------------------------------------------------------------------------
__global__ __launch_bounds__(128) void k_reduce(const float* __restrict__ part,
                                                const float* __restrict__ cntp,
                                                float* __restrict__ pe) {
  const int r = blockIdx.x;
  const int t = threadIdx.x;
  const float* pp = part + (size_t)r * HD + t;
  float s = 0.f;
#pragma unroll 6
  for (int kc = 0; kc < NKC; ++kc) s += pp[(size_t)kc * (MD * HD)];
  float c = 0.f;
#pragma unroll 6
  for (int kc = 0; kc < NKC; ++kc) c += cntp[kc * MD + r];
  pe[r * HD + t] = (c > 0.f) ? (s / c) : 0.f;
}

// ---------------------------------------------------------------------------
// Kernel 4: mean over P, then LN -> FC1 -> ReLU -> BN -> LN -> FC2 -> ReLU -> BN
// ---------------------------------------------------------------------------
__global__ __launch_bounds__(128) void k_tail(
    const float* __restrict__ pe,
    const float* __restrict__ w1, const float* __restrict__ b1,
    const float* __restrict__ w2, const float* __restrict__ b2,
    const float* __restrict__ ln1g, const float* __restrict__ ln1b,
    const float* __restrict__ ln2g, const float* __restrict__ ln2b,
    const float* __restrict__ bn1g, const float* __restrict__ bn1b,
    const float* __restrict__ bn2g, const float* __restrict__ bn2b,
    float* __restrict__ out) {
  const int b = blockIdx.x, t = threadIdx.x;
  __shared__ float sh[HD];
  __shared__ float red[HD];

  float x = 0.f;
#pragma unroll
  for (int p = 0; p < PD; ++p) x += pe[(b * PD + p) * HD + t];
  x *= (1.f / PD);

  const float bninv = rsqrtf(1.f + EPSF);

  // ---- LN1 ----
  red[t] = x; __syncthreads();
  for (int o = 64; o > 0; o >>= 1) { if (t < o) red[t] += red[t + o]; __syncthreads(); }
  const float mu1 = red[0] * (1.f / HD); __syncthreads();
  const float d1 = x - mu1;
  red[t] = d1 * d1; __syncthreads();
  for (int o = 64; o > 0; o >>= 1) { if (t < o) red[t] += red[t + o]; __syncthreads(); }
  const float v1 = red[0] * (1.f / HD); __syncthreads();
  const float y1 = ln1g[t] * d1 * rsqrtf(v1 + EPSF) + ln1b[t];

  // ---- FC1 + ReLU + BN1 ----
  sh[t] = y1; __syncthreads();
  float a = b1[t];
  const float4* wrow1 = (const float4*)(w1 + (size_t)t * HD);
#pragma unroll 8
  for (int k = 0; k < 32; ++k) {
    const float4 w = wrow1[k];
    a += w.x * sh[k * 4] + w.y * sh[k * 4 + 1] + w.z * sh[k * 4 + 2] + w.w * sh[k * 4 + 3];
  }
  a = fmaxf(a, 0.f);
  a = bn1g[t] * a * bninv + bn1b[t];
  __syncthreads();   // done with sh

  // ---- LN2 ----
  red[t] = a; __syncthreads();
  for (int o = 64; o > 0; o >>= 1) { if (t < o) red[t] += red[t + o]; __syncthreads(); }
  const float mu2 = red[0] * (1.f / HD); __syncthreads();
  const float d2 = a - mu2;
  red[t] = d2 * d2; __syncthreads();
  for (int o = 64; o > 0; o >>= 1) { if (t < o) red[t] += red[t + o]; __syncthreads(); }
  const float v2 = red[0] * (1.f / HD); __syncthreads();
  const float y2 = ln2g[t] * d2 * rsqrtf(v2 + EPSF) + ln2b[t];

  // ---- FC2 + ReLU + BN2 ----
  sh[t] = y2; __syncthreads();
  float a2 = b2[t];
  const float4* wrow2 = (const float4*)(w2 + (size_t)t * HD);
#pragma unroll 8
  for (int k = 0; k < 32; ++k) {
    const float4 w = wrow2[k];
    a2 += w.x * sh[k * 4] + w.y * sh[k * 4 + 1] + w.z * sh[k * 4 + 2] + w.w * sh[k * 4 + 3];
  }
  a2 = fmaxf(a2, 0.f);
  a2 = bn2g[t] * a2 * bninv + bn2b[t];
  out[b * HD + t] = a2;
}

// ---------------------------------------------------------------------------
extern "C" void kernel_launch(void* const* d_in, const int* in_sizes, int n_in,
                              void* d_out, int out_size, void* d_ws, size_t ws_size,
                              hipStream_t stream) {
  const int*   inp  = (const int*)d_in[0];
  const float* emb  = (const float*)d_in[1];
  const float* w1   = (const float*)d_in[2];
  const float* b1   = (const float*)d_in[3];
  const float* w2   = (const float*)d_in[4];
  const float* b2   = (const float*)d_in[5];
  const float* ln1g = (const float*)d_in[6];
  const float* ln1b = (const float*)d_in[7];
  const float* ln2g = (const float*)d_in[8];
  const float* ln2b = (const float*)d_in[9];
  const float* bn1g = (const float*)d_in[10];
  const float* bn1b = (const float*)d_in[11];
  const float* bn2g = (const float*)d_in[12];
  const float* bn2b = (const float*)d_in[13];
  float* out = (float*)d_out;

  // workspace layout (30.51 MB total — same as round 1, proven to fit)
  char* ws = (char*)d_ws;
  uint16_t* embT = (uint16_t*)ws;                        // 50048*128*2 = 12,812,288 B
  float* part = (float*)(ws + 12812288);                 // 66*512*128*4 = 17,301,504 B
  float* cntp = (float*)(ws + 12812288 + 17301504);      // 66*512*4 = 135,168 B
  float* pe   = (float*)(ws + 12812288 + 17301504 + 135168); // 512*128*4 = 262,144 B

  k_embT<<<EP / 64, 256, 0, stream>>>(emb, embT);
  k_gemm<<<NKC * 32, 256, 0, stream>>>(inp, embT, part, cntp);
  k_reduce<<<MD, 128, 0, stream>>>(part, cntp, pe);
  k_tail<<<BD, 128, 0, stream>>>(pe, w1, b1, w2, b2, ln1g, ln1b, ln2g, ln2b,
                                 bn1g, bn1b, bn2g, bn2b, out);
}

// Round 3
// 67.771 us; speedup vs baseline: 1.6533x; 1.6533x over previous
//
#include <hip/hip_runtime.h>
#include <stdint.h>

// Problem: B=32, P=16, E=50000, H=128
#define E_DIM 50000
#define EP    50048          // E padded to multiple of 64
#define HD    128
#define BD    32
#define PD    16
#define MD    512            // B*P
#define BM    32             // rows per block
#define BK    64             // k per stage
#define KCHUNK 768           // 12 stages of BK=64
#define NKC   66             // ceil(EP/KCHUNK); last chunk = 128 (2 stages)
#define EPSF  1e-5f

typedef short short8 __attribute__((ext_vector_type(8)));   // 8 bf16 (4 VGPRs)
typedef float f32x4  __attribute__((ext_vector_type(4)));

__device__ __forceinline__ uint16_t f2bf(float f) {
  uint32_t u = __float_as_uint(f);
  u += 0x7FFFu + ((u >> 16) & 1u);           // round-to-nearest-even
  return (uint16_t)(u >> 16);
}

// ---------------------------------------------------------------------------
// Kernel 1: emb [E][H] fp32 -> embT [H][EP] bf16 (transposed, row0 zeroed,
// e >= E_DIM zero-padded). LDS tile transpose with XOR swizzle.
// ---------------------------------------------------------------------------
__global__ __launch_bounds__(256) void k_embT(const float* __restrict__ emb,
                                              uint16_t* __restrict__ embT) {
  __shared__ __align__(16) uint16_t lds[HD * 64];   // [h][e_local], swizzled
  const int t  = threadIdx.x;
  const int e0 = blockIdx.x * 64;

#pragma unroll
  for (int pass = 0; pass < 8; ++pass) {
    const int el = pass * 8 + (t >> 5);       // 0..63
    const int h  = (t & 31) * 4;              // 0..124
    const int eg = e0 + el;
    float4 v = {0.f, 0.f, 0.f, 0.f};
    if (eg < E_DIM && eg != 0)                // padding_idx=0 -> zero row
      v = *(const float4*)(emb + (size_t)eg * HD + h);
    const uint16_t q0 = f2bf(v.x), q1 = f2bf(v.y), q2 = f2bf(v.z), q3 = f2bf(v.w);
    lds[(h + 0) * 64 + (el ^ (((h + 0) & 7) << 3))] = q0;
    lds[(h + 1) * 64 + (el ^ (((h + 1) & 7) << 3))] = q1;
    lds[(h + 2) * 64 + (el ^ (((h + 2) & 7) << 3))] = q2;
    lds[(h + 3) * 64 + (el ^ (((h + 3) & 7) << 3))] = q3;
  }
  __syncthreads();
#pragma unroll
  for (int pass = 0; pass < 8; ++pass) {
    const int hr  = pass * 16 + (t >> 4);     // 0..127
    const int el4 = (t & 15) * 4;             // 0..60
    uint2 d = *(const uint2*)(lds + hr * 64 + (el4 ^ ((hr & 7) << 3)));
    *(uint2*)(embT + (size_t)hr * EP + e0 + el4) = d;
  }
}

// ---------------------------------------------------------------------------
// Kernel 2: LDS-staged partial GEMM, 2-phase pipeline, 1 barrier/stage.
// Block = 256 thr (4 waves). Tile: 32 rows x 128 cols x KCHUNK.
// Wave w -> cols w*32..w*32+31. acc = 2x2 f32x4.
// A: int32 mask, coalesced global->reg, convert {0,1}->bf16, ds_write swizzled.
// B: embT rows, coalesced global->reg (64B/thread), ds_write swizzled.
// All MFMA fragments come from LDS via XOR-swizzled ds_read_b128 (uniform
// bank spread). LDS = 2*4KB (A) + 2*16KB (B) = 40960 B -> 4 blocks/CU.
// ---------------------------------------------------------------------------
__global__ __launch_bounds__(256, 4) void k_gemm(const int* __restrict__ inp,
                                                 const uint16_t* __restrict__ embT,
                                                 float* __restrict__ part,
                                                 float* __restrict__ cntp) {
  __shared__ __align__(16) uint16_t ldsA[2][BM * BK];   // swizzled [32][64]
  __shared__ __align__(16) uint16_t ldsB[2][HD * BK];   // swizzled [128][64]

  const int t    = threadIdx.x;
  const int lane = t & 63;
  const int w    = t >> 6;

  // XCD-aware swizzle: 16 blocks sharing a kc (same B chunk) land on one XCD.
  // nwg = 1056 = 8 * 132, bijective.
  const int virt = (blockIdx.x & 7) * (NKC * 16 / 8) + (blockIdx.x >> 3);
  const int mb = virt & 15;
  const int kc = virt >> 4;
  const int e0 = kc * KCHUNK;
  const int nst = min(12, (EP - e0) >> 6);

  // --- A staging map: row sr (0..31), 8 ints starting at col sc ---
  const int sr = t >> 3;
  const int sc = (t & 7) * 8;
  const int* ap = inp + (size_t)(mb * BM + sr) * E_DIM + e0 + sc;
  const int aw = sr * 128 + (((t & 7) ^ (sr & 7)) << 4);   // swizzled byte off

  // --- B staging map: row bh (0..127), 4 x 16B blocks starting at bq ---
  const int bh = t >> 1;
  const int bq = (t & 1) * 4;
  const uint16_t* bp = embT + (size_t)bh * EP + e0 + bq * 8;
  const int bw0 = bh * 128 + (((bq + 0) ^ (bh & 7)) << 4);
  const int bw1 = bh * 128 + (((bq + 1) ^ (bh & 7)) << 4);
  const int bw2 = bh * 128 + (((bq + 2) ^ (bh & 7)) << 4);
  const int bw3 = bh * 128 + (((bq + 3) ^ (bh & 7)) << 4);

  // --- compute-side read offsets ---
  const int r16 = lane & 15;
  const int kg  = (lane >> 4) << 3;          // 0,8,16,24
  const int aoff = r16 * 128;                // + ((cblk^sw)<<4), +2048 for mf=1
  const int boff = (w * 32 + r16) * 128;     // + ((cblk^sw)<<4), +2048 for hf=1
  const int swr  = r16 & 7;

  f32x4 acc00 = {0.f,0.f,0.f,0.f}, acc01 = {0.f,0.f,0.f,0.f};
  f32x4 acc10 = {0.f,0.f,0.f,0.f}, acc11 = {0.f,0.f,0.f,0.f};
  uint32_t cnt = 0;

  // ---- prologue: stage 0 ----
  {
    int4 a0 = {0,0,0,0}, a1 = {0,0,0,0};
    if (e0 + sc < E_DIM) { a0 = *(const int4*)ap; a1 = *(const int4*)(ap + 4); }
    const short8 v0 = *(const short8*)(bp);
    const short8 v1 = *(const short8*)(bp + 8);
    const short8 v2 = *(const short8*)(bp + 16);
    const short8 v3 = *(const short8*)(bp + 24);
    const uint32_t w01 = (uint32_t)a0.x | ((uint32_t)a0.y << 16);
    const uint32_t w23 = (uint32_t)a0.z | ((uint32_t)a0.w << 16);
    const uint32_t w45 = (uint32_t)a1.x | ((uint32_t)a1.y << 16);
    const uint32_t w67 = (uint32_t)a1.z | ((uint32_t)a1.w << 16);
    cnt += w01 + w23 + w45 + w67;
    uint4 d = { w01 * 0x3F80u, w23 * 0x3F80u, w45 * 0x3F80u, w67 * 0x3F80u };
    *(uint4*)((char*)ldsA[0] + aw) = d;
    *(short8*)((char*)ldsB[0] + bw0) = v0;
    *(short8*)((char*)ldsB[0] + bw1) = v1;
    *(short8*)((char*)ldsB[0] + bw2) = v2;
    *(short8*)((char*)ldsB[0] + bw3) = v3;
    __syncthreads();
  }

  for (int s = 0; s < nst; ++s) {
    const int cur = s & 1;
    const int nxt = cur ^ 1;
    const bool hn = (s + 1 < nst);
    int4 a0 = {0,0,0,0}, a1 = {0,0,0,0};
    short8 v0, v1, v2, v3;
    if (hn) {
      const int off = (s + 1) * 64;
      if (e0 + off + sc < E_DIM) {
        a0 = *(const int4*)(ap + off);
        a1 = *(const int4*)(ap + off + 4);
      }
      v0 = *(const short8*)(bp + off);
      v1 = *(const short8*)(bp + off + 8);
      v2 = *(const short8*)(bp + off + 16);
      v3 = *(const short8*)(bp + off + 24);
    }

    // ---- MFMA on current buffer ----
#pragma unroll
    for (int kk = 0; kk < 64; kk += 32) {
      const int cblk = (kk + kg) >> 3;
      const int sw16 = (cblk ^ swr) << 4;
      const short8 af0 = *(const short8*)((const char*)ldsA[cur] + aoff + sw16);
      const short8 af1 = *(const short8*)((const char*)ldsA[cur] + aoff + sw16 + 2048);
      const short8 bf0 = *(const short8*)((const char*)ldsB[cur] + boff + sw16);
      const short8 bf1 = *(const short8*)((const char*)ldsB[cur] + boff + sw16 + 2048);
      acc00 = __builtin_amdgcn_mfma_f32_16x16x32_bf16(af0, bf0, acc00, 0, 0, 0);
      acc01 = __builtin_amdgcn_mfma_f32_16x16x32_bf16(af0, bf1, acc01, 0, 0, 0);
      acc10 = __builtin_amdgcn_mfma_f32_16x16x32_bf16(af1, bf0, acc10, 0, 0, 0);
      acc11 = __builtin_amdgcn_mfma_f32_16x16x32_bf16(af1, bf1, acc11, 0, 0, 0);
    }

    if (hn) {
      const uint32_t w01 = (uint32_t)a0.x | ((uint32_t)a0.y << 16);
      const uint32_t w23 = (uint32_t)a0.z | ((uint32_t)a0.w << 16);
      const uint32_t w45 = (uint32_t)a1.x | ((uint32_t)a1.y << 16);
      const uint32_t w67 = (uint32_t)a1.z | ((uint32_t)a1.w << 16);
      cnt += w01 + w23 + w45 + w67;
      uint4 d = { w01 * 0x3F80u, w23 * 0x3F80u, w45 * 0x3F80u, w67 * 0x3F80u };
      *(uint4*)((char*)ldsA[nxt] + aw) = d;
      *(short8*)((char*)ldsB[nxt] + bw0) = v0;
      *(short8*)((char*)ldsB[nxt] + bw1) = v1;
      *(short8*)((char*)ldsB[nxt] + bw2) = v2;
      *(short8*)((char*)ldsB[nxt] + bw3) = v3;
    }
    __syncthreads();
  }

  // ---- epilogue: partial tile [kc][row][col] fp32 ----
  {
    const int jr = (lane >> 4) << 2;                       // C/D row group
    float* pt0 = part + (size_t)kc * (MD * HD)
               + (size_t)(mb * BM + jr) * HD + w * 32 + r16;
#pragma unroll
    for (int j = 0; j < 4; ++j) {
      pt0[j * HD]             = acc00[j];
      pt0[j * HD + 16]        = acc01[j];
      pt0[(16 + j) * HD]      = acc10[j];
      pt0[(16 + j) * HD + 16] = acc11[j];
    }
  }

  // ---- per-row mask counts: 8 consecutive lanes share a row ----
  {
    int c = (int)((cnt & 0xFFFFu) + (cnt >> 16));
    c += __shfl_xor(c, 1);
    c += __shfl_xor(c, 2);
    c += __shfl_xor(c, 4);
    if ((lane & 7) == 0)
      cntp[kc * MD + mb * BM + w * 8 + (lane >> 3)] = (float)c;
  }
}

// ---------------------------------------------------------------------------
// Kernel 3: reduce partials over kc -> path_emb [512][128]
// ---------------------------------------------------------------------------
__global__ __launch_bounds__(128) void k_reduce(const float* __restrict__ part,
                                                const float* __restrict__ cntp,
                                                float* __restrict__ pe) {
  const int r = blockIdx.x;
  const int t = threadIdx.x;
  const float* pp = part + (size_t)r * HD + t;
  float s = 0.f;
#pragma unroll 6
  for (int kc = 0; kc < NKC; ++kc) s += pp[(size_t)kc * (MD * HD)];
  float c = 0.f;
#pragma unroll 6
  for (int kc = 0; kc < NKC; ++kc) c += cntp[kc * MD + r];
  pe[r * HD + t] = (c > 0.f) ? (s / c) : 0.f;
}

// ---------------------------------------------------------------------------
// Kernel 4: mean over P, then LN -> FC1 -> ReLU -> BN -> LN -> FC2 -> ReLU -> BN
// ---------------------------------------------------------------------------
__global__ __launch_bounds__(128) void k_tail(
    const float* __restrict__ pe,
    const float* __restrict__ w1, const float* __restrict__ b1,
    const float* __restrict__ w2, const float* __restrict__ b2,
    const float* __restrict__ ln1g, const float* __restrict__ ln1b,
    const float* __restrict__ ln2g, const float* __restrict__ ln2b,
    const float* __restrict__ bn1g, const float* __restrict__ bn1b,
    const float* __restrict__ bn2g, const float* __restrict__ bn2b,
    float* __restrict__ out) {
  const int b = blockIdx.x, t = threadIdx.x;
  __shared__ float sh[HD];
  __shared__ float red[HD];

  float x = 0.f;
#pragma unroll
  for (int p = 0; p < PD; ++p) x += pe[(b * PD + p) * HD + t];
  x *= (1.f / PD);

  const float bninv = rsqrtf(1.f + EPSF);

  // ---- LN1 ----
  red[t] = x; __syncthreads();
  for (int o = 64; o > 0; o >>= 1) { if (t < o) red[t] += red[t + o]; __syncthreads(); }
  const float mu1 = red[0] * (1.f / HD); __syncthreads();
  const float d1 = x - mu1;
  red[t] = d1 * d1; __syncthreads();
  for (int o = 64; o > 0; o >>= 1) { if (t < o) red[t] += red[t + o]; __syncthreads(); }
  const float v1 = red[0] * (1.f / HD); __syncthreads();
  const float y1 = ln1g[t] * d1 * rsqrtf(v1 + EPSF) + ln1b[t];

  // ---- FC1 + ReLU + BN1 ----
  sh[t] = y1; __syncthreads();
  float a = b1[t];
  const float4* wrow1 = (const float4*)(w1 + (size_t)t * HD);
#pragma unroll 8
  for (int k = 0; k < 32; ++k) {
    const float4 w = wrow1[k];
    a += w.x * sh[k * 4] + w.y * sh[k * 4 + 1] + w.z * sh[k * 4 + 2] + w.w * sh[k * 4 + 3];
  }
  a = fmaxf(a, 0.f);
  a = bn1g[t] * a * bninv + bn1b[t];
  __syncthreads();   // done with sh

  // ---- LN2 ----
  red[t] = a; __syncthreads();
  for (int o = 64; o > 0; o >>= 1) { if (t < o) red[t] += red[t + o]; __syncthreads(); }
  const float mu2 = red[0] * (1.f / HD); __syncthreads();
  const float d2 = a - mu2;
  red[t] = d2 * d2; __syncthreads();
  for (int o = 64; o > 0; o >>= 1) { if (t < o) red[t] += red[t + o]; __syncthreads(); }
  const float v2 = red[0] * (1.f / HD); __syncthreads();
  const float y2 = ln2g[t] * d2 * rsqrtf(v2 + EPSF) + ln2b[t];

  // ---- FC2 + ReLU + BN2 ----
  sh[t] = y2; __syncthreads();
  float a2 = b2[t];
  const float4* wrow2 = (const float4*)(w2 + (size_t)t * HD);
#pragma unroll 8
  for (int k = 0; k < 32; ++k) {
    const float4 w = wrow2[k];
    a2 += w.x * sh[k * 4] + w.y * sh[k * 4 + 1] + w.z * sh[k * 4 + 2] + w.w * sh[k * 4 + 3];
  }
  a2 = fmaxf(a2, 0.f);
  a2 = bn2g[t] * a2 * bninv + bn2b[t];
  out[b * HD + t] = a2;
}

// ---------------------------------------------------------------------------
extern "C" void kernel_launch(void* const* d_in, const int* in_sizes, int n_in,
                              void* d_out, int out_size, void* d_ws, size_t ws_size,
                              hipStream_t stream) {
  const int*   inp  = (const int*)d_in[0];
  const float* emb  = (const float*)d_in[1];
  const float* w1   = (const float*)d_in[2];
  const float* b1   = (const float*)d_in[3];
  const float* w2   = (const float*)d_in[4];
  const float* b2   = (const float*)d_in[5];
  const float* ln1g = (const float*)d_in[6];
  const float* ln1b = (const float*)d_in[7];
  const float* ln2g = (const float*)d_in[8];
  const float* ln2b = (const float*)d_in[9];
  const float* bn1g = (const float*)d_in[10];
  const float* bn1b = (const float*)d_in[11];
  const float* bn2g = (const float*)d_in[12];
  const float* bn2b = (const float*)d_in[13];
  float* out = (float*)d_out;

  // workspace layout (30.51 MB total — proven to fit)
  char* ws = (char*)d_ws;
  uint16_t* embT = (uint16_t*)ws;                        // 50048*128*2 = 12,812,288 B
  float* part = (float*)(ws + 12812288);                 // 66*512*128*4 = 17,301,504 B
  float* cntp = (float*)(ws + 12812288 + 17301504);      // 66*512*4 = 135,168 B
  float* pe   = (float*)(ws + 12812288 + 17301504 + 135168); // 512*128*4 = 262,144 B

  k_embT<<<EP / 64, 256, 0, stream>>>(emb, embT);
  k_gemm<<<NKC * 16, 256, 0, stream>>>(inp, embT, part, cntp);
  k_reduce<<<MD, 128, 0, stream>>>(part, cntp, pe);
  k_tail<<<BD, 128, 0, stream>>>(pe, w1, b1, w2, b2, ln1g, ln1b, ln2g, ln2b,
                                 bn1g, bn1b, bn2g, bn2b, out);
}

// Round 5
// 59.642 us; speedup vs baseline: 1.8787x; 1.1363x over previous
//
#include <hip/hip_runtime.h>
#include <stdint.h>

// Problem: B=32, P=16, E=50000, H=128
#define E_DIM 50000
#define EP    50048          // E padded to multiple of 64
#define HD    128
#define BD    32
#define PD    16
#define MD    512            // B*P
#define BM    32             // rows per block
#define BK    64             // k per stage
#define KCHUNK 768           // 12 stages of BK=64
#define NKC   66             // ceil(EP/KCHUNK); last chunk = 128 (2 stages, even)
#define NST   12
#define EPSF  1e-5f

typedef short short8 __attribute__((ext_vector_type(8)));   // 8 bf16 (4 VGPRs)
typedef float f32x4  __attribute__((ext_vector_type(4)));

__device__ __forceinline__ uint16_t f2bf(float f) {
  uint32_t u = __float_as_uint(f);
  u += 0x7FFFu + ((u >> 16) & 1u);           // round-to-nearest-even
  return (uint16_t)(u >> 16);
}

// ---------------------------------------------------------------------------
// Kernel 1: emb [E][H] fp32 -> embF MFMA-fragment-packed bf16.
// Block bid covers e0 = bid*64 (bid = kc*12 + s). Output region per block:
// 16 fragments of 1 KB: [w:4][fr:4][lane:64][8 bf16], where
// fr = kk*2+hfl, h = (2w+hfl)*16 + (lane&15), e = e0 + kk*32 + (lane>>4)*8 + j.
// Row e=0 zeroed (padding_idx), e >= E_DIM zero-padded.
// ---------------------------------------------------------------------------
__global__ __launch_bounds__(256) void k_embF(const float* __restrict__ emb,
                                              uint16_t* __restrict__ embF) {
  __shared__ __align__(16) uint16_t lds[HD * 64];   // [h][e_local], swizzled
  const int t  = threadIdx.x;
  const int e0 = blockIdx.x * 64;

#pragma unroll
  for (int pass = 0; pass < 8; ++pass) {
    const int el = pass * 8 + (t >> 5);       // 0..63
    const int h  = (t & 31) * 4;              // 0..124
    const int eg = e0 + el;
    float4 v = {0.f, 0.f, 0.f, 0.f};
    if (eg < E_DIM && eg != 0)                // padding_idx=0 -> zero row
      v = *(const float4*)(emb + (size_t)eg * HD + h);
    const uint16_t q0 = f2bf(v.x), q1 = f2bf(v.y), q2 = f2bf(v.z), q3 = f2bf(v.w);
    lds[(h + 0) * 64 + (el ^ (((h + 0) & 7) << 3))] = q0;
    lds[(h + 1) * 64 + (el ^ (((h + 1) & 7) << 3))] = q1;
    lds[(h + 2) * 64 + (el ^ (((h + 2) & 7) << 3))] = q2;
    lds[(h + 3) * 64 + (el ^ (((h + 3) & 7) << 3))] = q3;
  }
  __syncthreads();

  const int w    = t >> 6;
  const int lane = t & 63;
  const int r16  = lane & 15;
  const int kgq  = (lane >> 4) * 8;
  uint16_t* outp = embF + (size_t)blockIdx.x * 8192 + (size_t)w * 2048 + lane * 8;
#pragma unroll
  for (int fr = 0; fr < 4; ++fr) {
    const int h  = (2 * w + (fr & 1)) * 16 + r16;
    const int el = (fr >> 1) * 32 + kgq;
    // el % 8 == 0 and the XOR swizzle only touches bits 3..5, so the
    // 8-element (16 B) group stays contiguous after swizzle.
    short8 d = *(const short8*)(lds + h * 64 + (el ^ ((h & 7) << 3)));
    *(short8*)(outp + fr * 512) = d;
  }
}

// ---------------------------------------------------------------------------
// Kernel 2: partial GEMM, counted-waitcnt pipeline (raw s_barrier, only
// lgkmcnt drained). A (mask): coalesced global->reg 2 stages ahead,
// convert {0,1}->bf16, swizzled ds_write, fragments read from 8 KB LDS
// double buffer. B: fragment-packed embF, global->reg 1 stage ahead, 4 KB
// contiguous per wave per stage — never touches LDS, flies across barriers.
// ---------------------------------------------------------------------------
__global__ __launch_bounds__(256, 4) void k_gemm(const int* __restrict__ inp,
                                                 const uint16_t* __restrict__ embF,
                                                 float* __restrict__ part,
                                                 float* __restrict__ cntp) {
  __shared__ __align__(16) uint16_t ldsA[2][BM * BK];   // 2 x 4 KB, swizzled

  const int t    = threadIdx.x;
  const int lane = t & 63;
  const int w    = t >> 6;

  // XCD-aware swizzle: 16 blocks sharing a kc land on one XCD (1056 = 8*132).
  const int virt = (blockIdx.x & 7) * (NKC * 16 / 8) + (blockIdx.x >> 3);
  const int mb = virt & 15;
  const int kc = virt >> 4;
  const int e0 = kc * KCHUNK;
  const int nst = min(NST, (EP - e0) >> 6);   // 12 or 2 (always even)

  // --- A staging map: row sr (0..31), 8 ints at col sc ---
  const int sr = t >> 3;
  const int sc = (t & 7) * 8;
  const int* ap = inp + (size_t)(mb * BM + sr) * E_DIM + e0 + sc;
  const int aw = sr * 128 + (((t & 7) ^ (sr & 7)) << 4);   // swizzled byte off

  // --- B fragment base: per (kc, s, w): 4 x 1 KB contiguous ---
  const uint16_t* bp = embF + ((size_t)kc * NST) * 8192 + (size_t)w * 2048 + lane * 8;

  // --- compute-side LDS read offsets ---
  const int r16  = lane & 15;
  const int kg   = (lane >> 4) << 3;          // 0,8,16,24
  const int aoff = r16 * 128;
  const int swr  = r16 & 7;

  f32x4 acc00 = {0.f,0.f,0.f,0.f}, acc01 = {0.f,0.f,0.f,0.f};
  f32x4 acc10 = {0.f,0.f,0.f,0.f}, acc11 = {0.f,0.f,0.f,0.f};
  uint32_t cnt = 0;

  // pending regs (all statically indexed)
  int4 aP0x, aP0y, aP1x, aP1y;       // A for even-parity / odd-parity stages
  short8 bP0[4], bP1[4];             // B for even / odd stages

#define LOAD_A(DSTX, DSTY, SIG)                                   \
  DSTX = (int4){0,0,0,0}; DSTY = (int4){0,0,0,0};                 \
  if (e0 + (SIG) * 64 + sc < E_DIM) {                             \
    DSTX = *(const int4*)(ap + (SIG) * 64);                       \
    DSTY = *(const int4*)(ap + (SIG) * 64 + 4);                   \
  }

#define LOAD_B(DST, SIG)                                          \
  _Pragma("unroll")                                               \
  for (int fr = 0; fr < 4; ++fr)                                  \
    DST[fr] = *(const short8*)(bp + (size_t)(SIG) * 8192 + fr * 512);

#define CONVERT_WRITE_A(SRCX, SRCY, BUF, SIG)                     \
  {                                                               \
    const uint32_t w01 = (uint32_t)SRCX.x | ((uint32_t)SRCX.y << 16); \
    const uint32_t w23 = (uint32_t)SRCX.z | ((uint32_t)SRCX.w << 16); \
    const uint32_t w45 = (uint32_t)SRCY.x | ((uint32_t)SRCY.y << 16); \
    const uint32_t w67 = (uint32_t)SRCY.z | ((uint32_t)SRCY.w << 16); \
    cnt += w01 + w23 + w45 + w67;                                 \
    uint4 d = { w01 * 0x3F80u, w23 * 0x3F80u, w45 * 0x3F80u, w67 * 0x3F80u }; \
    *(uint4*)((char*)ldsA[BUF] + aw) = d;                         \
  }

#define BARRIER()                                                 \
  asm volatile("s_waitcnt lgkmcnt(0)" ::: "memory");              \
  __builtin_amdgcn_s_barrier();                                   \
  __builtin_amdgcn_sched_barrier(0);

#define MFMA_STAGE(BUF, BREG)                                     \
  _Pragma("unroll")                                               \
  for (int kk = 0; kk < 2; ++kk) {                                \
    const int sw16 = (((kk * 4) + (kg >> 3)) ^ swr) << 4;         \
    const short8 af0 = *(const short8*)((const char*)ldsA[BUF] + aoff + sw16); \
    const short8 af1 = *(const short8*)((const char*)ldsA[BUF] + aoff + sw16 + 2048); \
    acc00 = __builtin_amdgcn_mfma_f32_16x16x32_bf16(af0, BREG[kk*2+0], acc00, 0, 0, 0); \
    acc01 = __builtin_amdgcn_mfma_f32_16x16x32_bf16(af0, BREG[kk*2+1], acc01, 0, 0, 0); \
    acc10 = __builtin_amdgcn_mfma_f32_16x16x32_bf16(af1, BREG[kk*2+0], acc10, 0, 0, 0); \
    acc11 = __builtin_amdgcn_mfma_f32_16x16x32_bf16(af1, BREG[kk*2+1], acc11, 0, 0, 0); \
  }

  // ---- prologue ----
  LOAD_A(aP0x, aP0y, 0)              // A(0) -> parity 0
  LOAD_A(aP1x, aP1y, 1)              // A(1) -> parity 1
  LOAD_B(bP0, 0)                     // B(0)
  CONVERT_WRITE_A(aP0x, aP0y, 0, 0)  // waits A(0) only (counted by compiler)
  BARRIER()

  // ---- main loop, 2-unrolled for static parity ----
  for (int s = 0; s < nst; s += 2) {
    // even phase: compute stage s (buf0, bP0)
    if (s + 2 < nst) { LOAD_A(aP0x, aP0y, s + 2) }      // A(s+2) -> parity 0
    if (s + 1 < nst) { LOAD_B(bP1, s + 1) }             // B(s+1)
    MFMA_STAGE(0, bP0)
    if (s + 1 < nst) { CONVERT_WRITE_A(aP1x, aP1y, 1, s + 1) }
    BARRIER()

    // odd phase: compute stage s+1 (buf1, bP1)
    if (s + 3 < nst) { LOAD_A(aP1x, aP1y, s + 3) }      // A(s+3) -> parity 1
    if (s + 2 < nst) { LOAD_B(bP0, s + 2) }             // B(s+2)
    if (s + 1 < nst) { MFMA_STAGE(1, bP1) }
    if (s + 2 < nst) { CONVERT_WRITE_A(aP0x, aP0y, 0, s + 2) }
    BARRIER()
  }

#undef LOAD_A
#undef LOAD_B
#undef CONVERT_WRITE_A
#undef BARRIER
#undef MFMA_STAGE

  // ---- epilogue: partial tile [kc][row][col] fp32 ----
  {
    const int jr = (lane >> 4) << 2;                       // C/D row group
    float* pt0 = part + (size_t)kc * (MD * HD)
               + (size_t)(mb * BM + jr) * HD + w * 32 + r16;
#pragma unroll
    for (int j = 0; j < 4; ++j) {
      pt0[j * HD]             = acc00[j];
      pt0[j * HD + 16]        = acc01[j];
      pt0[(16 + j) * HD]      = acc10[j];
      pt0[(16 + j) * HD + 16] = acc11[j];
    }
  }

  // ---- per-row mask counts: 8 consecutive lanes share a row ----
  {
    int c = (int)((cnt & 0xFFFFu) + (cnt >> 16));
    c += __shfl_xor(c, 1);
    c += __shfl_xor(c, 2);
    c += __shfl_xor(c, 4);
    if ((lane & 7) == 0)
      cntp[kc * MD + mb * BM + w * 8 + (lane >> 3)] = (float)c;
  }
}

// ---------------------------------------------------------------------------
// Kernel 3: reduce partials over kc -> path_emb [512][128]
// ---------------------------------------------------------------------------
__global__ __launch_bounds__(128) void k_reduce(const float* __restrict__ part,
                                                const float* __restrict__ cntp,
                                                float* __restrict__ pe) {
  const int r = blockIdx.x;
  const int t = threadIdx.x;
  const float* pp = part + (size_t)r * HD + t;
  float s = 0.f;
#pragma unroll 6
  for (int kc = 0; kc < NKC; ++kc) s += pp[(size_t)kc * (MD * HD)];
  float c = 0.f;
#pragma unroll 6
  for (int kc = 0; kc < NKC; ++kc) c += cntp[kc * MD + r];
  pe[r * HD + t] = (c > 0.f) ? (s / c) : 0.f;
}

// ---------------------------------------------------------------------------
// Kernel 4: mean over P, then LN -> FC1 -> ReLU -> BN -> LN -> FC2 -> ReLU -> BN
// ---------------------------------------------------------------------------
__global__ __launch_bounds__(128) void k_tail(
    const float* __restrict__ pe,
    const float* __restrict__ w1, const float* __restrict__ b1,
    const float* __restrict__ w2, const float* __restrict__ b2,
    const float* __restrict__ ln1g, const float* __restrict__ ln1b,
    const float* __restrict__ ln2g, const float* __restrict__ ln2b,
    const float* __restrict__ bn1g, const float* __restrict__ bn1b,
    const float* __restrict__ bn2g, const float* __restrict__ bn2b,
    float* __restrict__ out) {
  const int b = blockIdx.x, t = threadIdx.x;
  __shared__ float sh[HD];
  __shared__ float red[HD];

  float x = 0.f;
#pragma unroll
  for (int p = 0; p < PD; ++p) x += pe[(b * PD + p) * HD + t];
  x *= (1.f / PD);

  const float bninv = rsqrtf(1.f + EPSF);

  // ---- LN1 ----
  red[t] = x; __syncthreads();
  for (int o = 64; o > 0; o >>= 1) { if (t < o) red[t] += red[t + o]; __syncthreads(); }
  const float mu1 = red[0] * (1.f / HD); __syncthreads();
  const float d1 = x - mu1;
  red[t] = d1 * d1; __syncthreads();
  for (int o = 64; o > 0; o >>= 1) { if (t < o) red[t] += red[t + o]; __syncthreads(); }
  const float v1 = red[0] * (1.f / HD); __syncthreads();
  const float y1 = ln1g[t] * d1 * rsqrtf(v1 + EPSF) + ln1b[t];

  // ---- FC1 + ReLU + BN1 ----
  sh[t] = y1; __syncthreads();
  float a = b1[t];
  const float4* wrow1 = (const float4*)(w1 + (size_t)t * HD);
#pragma unroll 8
  for (int k = 0; k < 32; ++k) {
    const float4 w = wrow1[k];
    a += w.x * sh[k * 4] + w.y * sh[k * 4 + 1] + w.z * sh[k * 4 + 2] + w.w * sh[k * 4 + 3];
  }
  a = fmaxf(a, 0.f);
  a = bn1g[t] * a * bninv + bn1b[t];
  __syncthreads();   // done with sh

  // ---- LN2 ----
  red[t] = a; __syncthreads();
  for (int o = 64; o > 0; o >>= 1) { if (t < o) red[t] += red[t + o]; __syncthreads(); }
  const float mu2 = red[0] * (1.f / HD); __syncthreads();
  const float d2 = a - mu2;
  red[t] = d2 * d2; __syncthreads();
  for (int o = 64; o > 0; o >>= 1) { if (t < o) red[t] += red[t + o]; __syncthreads(); }
  const float v2 = red[0] * (1.f / HD); __syncthreads();
  const float y2 = ln2g[t] * d2 * rsqrtf(v2 + EPSF) + ln2b[t];

  // ---- FC2 + ReLU + BN2 ----
  sh[t] = y2; __syncthreads();
  float a2 = b2[t];
  const float4* wrow2 = (const float4*)(w2 + (size_t)t * HD);
#pragma unroll 8
  for (int k = 0; k < 32; ++k) {
    const float4 w = wrow2[k];
    a2 += w.x * sh[k * 4] + w.y * sh[k * 4 + 1] + w.z * sh[k * 4 + 2] + w.w * sh[k * 4 + 3];
  }
  a2 = fmaxf(a2, 0.f);
  a2 = bn2g[t] * a2 * bninv + bn2b[t];
  out[b * HD + t] = a2;
}

// ---------------------------------------------------------------------------
extern "C" void kernel_launch(void* const* d_in, const int* in_sizes, int n_in,
                              void* d_out, int out_size, void* d_ws, size_t ws_size,
                              hipStream_t stream) {
  const int*   inp  = (const int*)d_in[0];
  const float* emb  = (const float*)d_in[1];
  const float* w1   = (const float*)d_in[2];
  const float* b1   = (const float*)d_in[3];
  const float* w2   = (const float*)d_in[4];
  const float* b2   = (const float*)d_in[5];
  const float* ln1g = (const float*)d_in[6];
  const float* ln1b = (const float*)d_in[7];
  const float* ln2g = (const float*)d_in[8];
  const float* ln2b = (const float*)d_in[9];
  const float* bn1g = (const float*)d_in[10];
  const float* bn1b = (const float*)d_in[11];
  const float* bn2g = (const float*)d_in[12];
  const float* bn2b = (const float*)d_in[13];
  float* out = (float*)d_out;

  // workspace layout (30.67 MB total)
  char* ws = (char*)d_ws;
  uint16_t* embF = (uint16_t*)ws;                        // 792*16384 = 12,976,128 B
  float* part = (float*)(ws + 12976128);                 // 66*512*128*4 = 17,301,504 B
  float* cntp = (float*)(ws + 12976128 + 17301504);      // 66*512*4 = 135,168 B
  float* pe   = (float*)(ws + 12976128 + 17301504 + 135168); // 512*128*4 = 262,144 B

  k_embF<<<NKC * NST, 256, 0, stream>>>(emb, embF);
  k_gemm<<<NKC * 16, 256, 0, stream>>>(inp, embF, part, cntp);
  k_reduce<<<MD, 128, 0, stream>>>(part, cntp, pe);
  k_tail<<<BD, 128, 0, stream>>>(pe, w1, b1, w2, b2, ln1g, ln1b, ln2g, ln2b,
                                 bn1g, bn1b, bn2g, bn2b, out);
}